// Round 2
// baseline (137.412 us; speedup 1.0000x reference)
//
#include <hip/hip_runtime.h>
#include <hip/hip_bf16.h>
#include <stdint.h>

// Problem constants (B=8192, D=256 fixed by reference setup_inputs)
#define NB 8192          // batch rows
#define ND 256           // feature dim (= full K)
#define NW 16384         // rows of W = [v; u]
#define BM 128           // rows per block
#define BN 64            // cols per tile (barrier-free: wave slice = 16 rows = 8 KB)
#define NSTRIP 4         // column strips
#define STRIPW 4096      // cols per strip
#define NTILES (STRIPW / BN)   // 64 tiles per block
// rows pre-scaled by rw*sqrt(1/T): every dot product == sim/T directly
#define SQRT_INVT 3.7796447f   // sqrt(1/0.07)

typedef __bf16 bf16x8 __attribute__((ext_vector_type(8)));
typedef float floatx4 __attribute__((ext_vector_type(4)));

__device__ __forceinline__ void gload_lds16(const void* g, void* l) {
    // async global->LDS, 16B per lane; LDS dest = wave-uniform base + lane*16
    __builtin_amdgcn_global_load_lds(
        (const __attribute__((address_space(1))) unsigned int*)g,
        (__attribute__((address_space(3))) unsigned int*)l,
        16, 0, 0);
}

// ---------------------------------------------------------------------------
// Kernel 1: W[row] = concat(v,u)[row] * (1/||row||) * sqrt(1/T), in bf16.
// One WAVE per row: float4 loads, shuffle reduce, ushort4 store.
// ---------------------------------------------------------------------------
__global__ __launch_bounds__(512) void prep_kernel(
    const float* __restrict__ u, const float* __restrict__ v,
    __hip_bfloat16* __restrict__ W)
{
    const int t    = threadIdx.x;
    const int row  = blockIdx.x * 8 + (t >> 6);       // 0..16383
    const int lane = t & 63;
    const float* src = (row < NB) ? (v + (size_t)row * ND)
                                  : (u + (size_t)(row - NB) * ND);
    float4 x = ((const float4*)src)[lane];
    float ss = x.x * x.x + x.y * x.y + x.z * x.z + x.w * x.w;
#pragma unroll
    for (int off = 1; off < 64; off <<= 1) ss += __shfl_xor(ss, off, 64);
    const float sc = rsqrtf(ss) * SQRT_INVT;          // norms ~16, eps clamp moot
    ushort4 o;
    __hip_bfloat16 h;
    h = __float2bfloat16(x.x * sc); o.x = *(const unsigned short*)&h;
    h = __float2bfloat16(x.y * sc); o.y = *(const unsigned short*)&h;
    h = __float2bfloat16(x.z * sc); o.z = *(const unsigned short*)&h;
    h = __float2bfloat16(x.w * sc); o.w = *(const unsigned short*)&h;
    ((ushort4*)(W + (size_t)row * ND))[lane] = o;
}

// ---------------------------------------------------------------------------
// Kernel 2: persistent fused GEMM+exp+rowsum -- BARRIER-FREE main loop.
// Grid = 256 blocks (1/CU) x 512 threads (8 waves).
// Block owns (row-tile rt, strip s): rows [rt*128,+128), cols [s*4096,+4096).
// A (128x256 full-K) staged once cooperatively -> af[] registers (64 VGPR).
// NEW vs round-1 baseline (73.7us, MfmaUtil 36.6%): the 2-phase lockstep
// (1 barrier + vmcnt(0) drain per 128x128 tile, 8-wave convoy) was the
// bottleneck, not LDS banks (0 conflicts) nor memory (2.9% HBM). Now each
// wave stages its OWN 16 B-rows (8 KB) into a PRIVATE LDS double buffer:
// no __syncthreads in the main loop at all. Waves drift apart -> natural
// pipeline diversity; s_setprio(1) around the MFMA cluster now has waves
// to arbitrate between (T5 regime gate). Epilogue exp of tile t-1 is
// deferred and interleaved (branchless, same basic block) into tile t's
// MFMA shadow. Diagonal tiles handled by a rare wave-uniform FIXUP that
// subtracts the same exp value it added (exact operand -> ~1e-6 error).
// Cost: B staging duplicated x2 (wm pair) = 4 MB/CU from L2 (29.6 us at
// 135 GB/s/CU) -- fits under the 33 us MFMA floor.
// LDS swizzle unchanged (chunk c of row r at c^(r&15); here r<16 so c^r).
// ---------------------------------------------------------------------------
__global__ __launch_bounds__(512, 2) void dcl_main(
    const __hip_bfloat16* __restrict__ W,   // 16384 x 256, pre-scaled
    float* __restrict__ partial,            // [4][8192] slot = strip
    float* __restrict__ pos)                // 8192
{
    const int b  = blockIdx.x;
    const int s  = (b >> 1) & 3;                    // strip; XCD(b)=b%8 in {2s,2s+1}
    const int rt = ((b >> 3) << 1) | (b & 1);       // row tile 0..63
    const int rb = rt * BM;

    const __hip_bfloat16* A = W + (size_t)NB * ND;  // u rows

    __shared__ __align__(16) char lds[131072];

    const int tid  = threadIdx.x;
    const int wave = tid >> 6;
    const int lane = tid & 63;
    const int wm   = wave >> 2;             // 0..1 : 64-row group of A
    const int wn   = wave & 3;              // 0..3 : 16-col group of tile
    const int quad = lane >> 4;             // 0..3
    const int tcol = lane & 15;             // 0..15
    const int cc   = lane & 31;             // stage: 16B chunk index
    const int rh   = lane >> 5;             // stage: row half

    // ---- stage A (->lds[0:64K), swizzled, cooperative) ----
#pragma unroll
    for (int i = 0; i < 8; i++) {
        int o = i * 8192 + wave * 1024 + lane * 16;
        int r = o >> 9;                          // 512 B per row
        int c = (o >> 4) & 31;                   // 32 chunks of 16 B
        int cg = (c ^ (r & 15)) * 8;             // swizzled global k-offset
        gload_lds16(A + (size_t)(rb + r) * ND + cg, lds + i * 8192 + wave * 1024);
    }
    __syncthreads();    // drains vmcnt: A resident

    // ---- A fragments -> registers (64 VGPRs), reused for all 64 tiles ----
    bf16x8 af[4][8];
#pragma unroll
    for (int mt = 0; mt < 4; mt++) {
        int r = wm * 64 + mt * 16 + tcol;
#pragma unroll
        for (int ks = 0; ks < 8; ks++) {
            int c = (ks * 4 + quad) ^ (r & 15);
            af[mt][ks] = *(const bf16x8*)(lds + r * 512 + (c << 4));
        }
    }
    __syncthreads();    // all waves done reading A before B staging overwrites

    // per-wave private double buffer: 2 x 8 KB
    char* const wbuf  = lds + wave * 16384;
    const int   sbase = s * STRIPW;

    // diag tile (wave-uniform): pcb == rb + wm*64 (uv, strips 0-1) or +NB (uu)
    const bool isuv = (s < 2);
    int dp = rb + wm * 64 + (isuv ? 0 : NB);
    if ((dp >> 12) != s) dp = 0x40000000;   // sentinel: never matches

    float rsum[4][4];
#pragma unroll
    for (int mt = 0; mt < 4; mt++)
#pragma unroll
        for (int rg = 0; rg < 4; rg++) rsum[mt][rg] = 0.f;

#define STAGE(t, half) do {                                                  \
    const int rowb_ = sbase + (t) * BN + wn * 16;                            \
    char* dst_ = wbuf + (half) * 8192;                                       \
    _Pragma("unroll")                                                        \
    for (int i_ = 0; i_ < 8; i_++) {                                         \
        int r_ = 2 * i_ + rh;                                                \
        gload_lds16(W + (size_t)(rowb_ + r_) * ND + ((cc ^ r_) << 3),        \
                    dst_ + i_ * 1024);                                       \
    }                                                                        \
} while (0)

#define EPI_CLEAN(accP) do {                                                 \
    _Pragma("unroll")                                                        \
    for (int mt_ = 0; mt_ < 4; mt_++)                                        \
        _Pragma("unroll")                                                    \
        for (int rg_ = 0; rg_ < 4; rg_++)                                    \
            rsum[mt_][rg_] += __expf(accP[mt_][rg_]);                        \
} while (0)

#define FIXUP(accP, cbP) do {                                                \
    if ((cbP) == dp) {                                                       \
        _Pragma("unroll")                                                    \
        for (int mt_ = 0; mt_ < 4; mt_++)                                    \
            _Pragma("unroll")                                                \
            for (int rg_ = 0; rg_ < 4; rg_++) {                              \
                int rl_ = mt_ * 16 + quad * 4 + rg_;                         \
                bool sel_ = (rl_ == wn * 16 + tcol);                         \
                float sc_ = accP[mt_][rg_];                                  \
                if (isuv && sel_) pos[rb + wm * 64 + rl_] = sc_;             \
                if (sel_) rsum[mt_][rg_] -= __expf(sc_);                     \
            }                                                                \
    }                                                                        \
} while (0)

#define COMPUTE(acc, bufp) do {                                              \
    _Pragma("unroll")                                                        \
    for (int mt_ = 0; mt_ < 4; mt_++) acc[mt_] = (floatx4){0.f,0.f,0.f,0.f}; \
    __builtin_amdgcn_s_setprio(1);                                           \
    _Pragma("unroll")                                                        \
    for (int ks_ = 0; ks_ < 8; ks_++) {                                      \
        bf16x8 bb_ = *(const bf16x8*)((bufp) + tcol * 512 +                  \
                                      ((((ks_ * 4) + quad) ^ tcol) << 4));   \
        _Pragma("unroll")                                                    \
        for (int mt_ = 0; mt_ < 4; mt_++)                                    \
            acc[mt_] = __builtin_amdgcn_mfma_f32_16x16x32_bf16(              \
                af[mt_][ks_], bb_, acc[mt_], 0, 0, 0);                       \
    }                                                                        \
    __builtin_amdgcn_s_setprio(0);                                           \
} while (0)

    floatx4 accA[4], accB[4];
#pragma unroll
    for (int mt = 0; mt < 4; mt++)
        accB[mt] = (floatx4){-1e38f, -1e38f, -1e38f, -1e38f};  // exp -> 0
    int cbA = -1, cbB = -1;

    STAGE(0, 0);

#pragma unroll 1
    for (int t2 = 0; t2 < NTILES; t2 += 2) {
        // ---- even tile t2: compute->accA from half0, finish accB ----
        asm volatile("s_waitcnt vmcnt(0)" ::: "memory");
        STAGE(t2 + 1, 1);
        __builtin_amdgcn_sched_barrier(0);
        EPI_CLEAN(accB);            // interleaves into MFMA shadow below
        COMPUTE(accA, wbuf);
        __builtin_amdgcn_sched_barrier(0);
        FIXUP(accB, cbB);
        cbA = sbase + t2 * BN;

        // ---- odd tile t2+1: compute->accB from half1, finish accA ----
        asm volatile("s_waitcnt vmcnt(0)" ::: "memory");
        if (t2 + 2 < NTILES) STAGE(t2 + 2, 0);
        __builtin_amdgcn_sched_barrier(0);
        EPI_CLEAN(accA);
        COMPUTE(accB, wbuf + 8192);
        __builtin_amdgcn_sched_barrier(0);
        FIXUP(accA, cbA);
        cbB = sbase + (t2 + 1) * BN;
    }
    EPI_CLEAN(accB);                // tile 63
    FIXUP(accB, cbB);

#undef STAGE
#undef EPI_CLEAN
#undef FIXUP
#undef COMPUTE

    __syncthreads();   // waves are desynced; resync before LDS reuse

    // block-end reduction: quad-lane shuffle, then combine the 4 wn waves in LDS
#pragma unroll
    for (int mt = 0; mt < 4; mt++)
#pragma unroll
        for (int reg = 0; reg < 4; reg++) {
            float vsum = rsum[mt][reg];
            vsum += __shfl_xor(vsum, 1, 64);
            vsum += __shfl_xor(vsum, 2, 64);
            vsum += __shfl_xor(vsum, 4, 64);
            vsum += __shfl_xor(vsum, 8, 64);
            if (tcol == 0) {
                int lrow = wm * 64 + mt * 16 + quad * 4 + reg;
                ((float*)lds)[wn * 128 + lrow] = vsum;
            }
        }
    __syncthreads();
    if (tid < BM) {
        const float* lf = (const float*)lds;
        float t = lf[tid] + lf[128 + tid] + lf[256 + tid] + lf[384 + tid];
        partial[(size_t)s * NB + rb + tid] = t;
    }
}

// ---------------------------------------------------------------------------
// Kernel 3: loss = mean_i( log(sum_strips partial[s][i]) - pos_i )
// ---------------------------------------------------------------------------
__global__ __launch_bounds__(1024) void finalize_kernel(
    const float* __restrict__ partial, const float* __restrict__ pos,
    float* __restrict__ out)
{
    const int t = threadIdx.x;
    float s = 0.f;
    for (int i = t; i < NB; i += 1024) {
        float tot = partial[i] + partial[NB + i] + partial[2 * NB + i]
                  + partial[3 * NB + i];
        s += logf(tot) - pos[i];
    }
#pragma unroll
    for (int off = 32; off > 0; off >>= 1) s += __shfl_down(s, off, 64);
    __shared__ float wsum[16];
    if ((t & 63) == 0) wsum[t >> 6] = s;
    __syncthreads();
    if (t == 0) {
        float tot = 0.f;
#pragma unroll
        for (int i = 0; i < 16; i++) tot += wsum[i];
        out[0] = tot / (float)NB;
    }
}

extern "C" void kernel_launch(void* const* d_in, const int* in_sizes, int n_in,
                              void* d_out, int out_size, void* d_ws, size_t ws_size,
                              hipStream_t stream) {
    const float* u = (const float*)d_in[0];
    const float* v = (const float*)d_in[1];
    float* out = (float*)d_out;

    char* ws = (char*)d_ws;
    __hip_bfloat16* W = (__hip_bfloat16*)ws;                      // 8 MB
    float* partial = (float*)(ws + (size_t)NW * ND * sizeof(__hip_bfloat16));
    float* pos     = partial + NSTRIP * NB;                       // 8192 floats

    prep_kernel<<<NW / 8, 512, 0, stream>>>(u, v, W);
    dcl_main<<<256, 512, 0, stream>>>(W, partial, pos);
    finalize_kernel<<<1, 1024, 0, stream>>>(partial, pos, out);
}